// Round 7
// baseline (81.882 us; speedup 1.0000x reference)
//
#include <hip/hip_runtime.h>

#define N_FLT 48
#define N_KNOTS 91
#define LDS_STRIDE 49   // pad 48->49 (R6): odd multiplier mod 32 spreads gather banks

typedef float f32x4 __attribute__((ext_vector_type(4)));  // native vec for nontemporal builtins

// Spline interpolation: out[i] = lerp over yk knots, per-channel (i % 48).
// Memory-bound elementwise; yk staged in LDS for the data-dependent gather.
// R2: nontemporal load/store. R3: ext_vector fix. R4: 2-stream MLP (76.8us best).
// R5: 4-stream regressed (VGPR>64 occupancy cliff) -> stay 2-stream.
// R6: LDS pad neutral -> LDS conflicts not critical path; keep pad.
// R7: block-contiguous chunks instead of grid-stride interleave. Grid-stride
//     jumps 8MB between a block's successive accesses; contiguous chunks let
//     each block stream sequentially through ~1.5MB -> better DRAM page hits.
__global__ __launch_bounds__(256) void spline_interp_kernel(
    const float* __restrict__ x,
    const float* __restrict__ yk,
    float* __restrict__ out,
    int n4)
{
    __shared__ float yk_s[N_KNOTS * LDS_STRIDE];
    for (int i = threadIdx.x; i < N_KNOTS * N_FLT; i += 256) {
        int r = i / N_FLT;
        int c = i - r * N_FLT;
        yk_s[r * LDS_STRIDE + c] = yk[i];
    }
    __syncthreads();

    // reference: clip(xS, 1e-5, N_KNOTS - 1.00001) = [1e-5, 89.99999]
    const float upper = (float)N_KNOTS - 1.00001f;  // 89.99999f

    const f32x4* xv4  = reinterpret_cast<const f32x4*>(x);
    f32x4*       out4 = reinterpret_cast<f32x4*>(out);

    // ---- block-contiguous main region: each block owns `per_block` float4s ----
    const int per_block = n4 / gridDim.x;        // 6144 in the bench shape
    const int half      = per_block / 2;         // two streams, one per chunk half
    const int base      = blockIdx.x * per_block;
    const int iters     = half / 256;            // 12

    for (int it = 0; it < iters; ++it) {
        const int iA = base + it * 256 + threadIdx.x;
        const int iB = iA + half;
        f32x4 xa = __builtin_nontemporal_load(xv4 + iA);
        f32x4 xb = __builtin_nontemporal_load(xv4 + iB);
        const int cA = (iA * 4) % N_FLT;   // 48%4==0 -> no wrap within a float4
        const int cB = (iB * 4) % N_FLT;

        f32x4 rA, rB;
#pragma unroll
        for (int j = 0; j < 4; ++j) {
            float xS = (xa[j] + 3.0f) * 15.0f;             // (x+3)/(6/90)
            xS = fminf(fmaxf(xS, 1e-5f), upper);
            float xF = floorf(xS);
            float k  = xS - xF;
            int  idx = (int)xF;                            // in [0,89] by clamp
            float yf = yk_s[idx * LDS_STRIDE + cA + j];
            float yc = yk_s[idx * LDS_STRIDE + LDS_STRIDE + cA + j];
            rA[j] = yf * (1.0f - k) + k * yc;
        }
#pragma unroll
        for (int j = 0; j < 4; ++j) {
            float xS = (xb[j] + 3.0f) * 15.0f;
            xS = fminf(fmaxf(xS, 1e-5f), upper);
            float xF = floorf(xS);
            float k  = xS - xF;
            int  idx = (int)xF;
            float yf = yk_s[idx * LDS_STRIDE + cB + j];
            float yc = yk_s[idx * LDS_STRIDE + LDS_STRIDE + cB + j];
            rB[j] = yf * (1.0f - k) + k * yc;
        }
        __builtin_nontemporal_store(rA, out4 + iA);
        __builtin_nontemporal_store(rB, out4 + iB);
    }

    // ---- generic tail: anything past gridDim.x * per_block (empty in bench) ----
    int idx4 = gridDim.x * per_block + blockIdx.x * 256 + threadIdx.x;
    const int gstride = gridDim.x * 256;
    for (; idx4 < n4; idx4 += gstride) {
        f32x4 xv = __builtin_nontemporal_load(xv4 + idx4);
        const int c0 = (idx4 * 4) % N_FLT;
        f32x4 r;
#pragma unroll
        for (int j = 0; j < 4; ++j) {
            float xS = (xv[j] + 3.0f) * 15.0f;
            xS = fminf(fmaxf(xS, 1e-5f), upper);
            float xF = floorf(xS);
            float k  = xS - xF;
            int  idx = (int)xF;
            float yf = yk_s[idx * LDS_STRIDE + c0 + j];
            float yc = yk_s[idx * LDS_STRIDE + LDS_STRIDE + c0 + j];
            r[j] = yf * (1.0f - k) + k * yc;
        }
        __builtin_nontemporal_store(r, out4 + idx4);
    }
}

extern "C" void kernel_launch(void* const* d_in, const int* in_sizes, int n_in,
                              void* d_out, int out_size, void* d_ws, size_t ws_size,
                              hipStream_t stream) {
    const float* x  = (const float*)d_in[0];
    const float* yk = (const float*)d_in[1];
    float* out = (float*)d_out;

    int n  = in_sizes[0];      // 16*256*256*48 = 50,331,648 (divisible by 4)
    int n4 = n / 4;

    const int block = 256;
    const int grid  = 2048;    // 256 CUs * 8 blocks; 6144 float4 per block

    spline_interp_kernel<<<grid, block, 0, stream>>>(x, yk, out, n4);
}

// Round 8
// 67.395 us; speedup vs baseline: 1.2150x; 1.2150x over previous
//
#include <hip/hip_runtime.h>

#define N_FLT 48
#define N_KNOTS 91
#define LDS_STRIDE 49   // pad 48->49 (R6): odd multiplier mod 32 spreads gather banks

typedef float f32x4 __attribute__((ext_vector_type(4)));  // native vec for nontemporal builtins

// Spline interpolation: out[i] = lerp over yk knots, per-channel (i % 48).
// Memory-bound elementwise; yk staged in LDS for the data-dependent gather.
// R2: nontemporal load/store. R3: ext_vector fix. R4: 2-stream MLP (76.8us best).
// R5: 4-stream regressed (VGPR occupancy cliff) -> stay 2-stream.
// R6: LDS pad neutral -> conflicts not critical; keep pad.
// R7: block-contiguous chunks regressed -> grid-stride interleave restored.
// R8: A/B the nt-load hint (was bundled with R4's unroll): plain loads
//     (L2-resident read stream), keep nt-stores (output never re-read).
__global__ __launch_bounds__(256) void spline_interp_kernel(
    const float* __restrict__ x,
    const float* __restrict__ yk,
    float* __restrict__ out,
    int n4)
{
    __shared__ float yk_s[N_KNOTS * LDS_STRIDE];
    for (int i = threadIdx.x; i < N_KNOTS * N_FLT; i += 256) {
        int r = i / N_FLT;
        int c = i - r * N_FLT;
        yk_s[r * LDS_STRIDE + c] = yk[i];
    }
    __syncthreads();

    // reference: clip(xS, 1e-5, N_KNOTS - 1.00001) = [1e-5, 89.99999]
    const float upper = (float)N_KNOTS - 1.00001f;  // 89.99999f

    const int tid    = blockIdx.x * 256 + threadIdx.x;
    const int stride = gridDim.x * 256;

    const f32x4* xv4  = reinterpret_cast<const f32x4*>(x);
    f32x4*       out4 = reinterpret_cast<f32x4*>(out);

    // main loop: 2 independent float4 streams per iteration (grid-stride)
    int idx4 = tid;
    for (; idx4 + stride < n4; idx4 += 2 * stride) {
        const int idxB = idx4 + stride;
        f32x4 xa = xv4[idx4];               // plain load (R8: no nt on reads)
        f32x4 xb = xv4[idxB];
        const int cA = (idx4 * 4) % N_FLT;  // 48%4==0 -> no wrap within float4
        const int cB = (idxB * 4) % N_FLT;

        f32x4 rA, rB;
#pragma unroll
        for (int j = 0; j < 4; ++j) {
            float xS = (xa[j] + 3.0f) * 15.0f;             // (x+3)/(6/90)
            xS = fminf(fmaxf(xS, 1e-5f), upper);
            float xF = floorf(xS);
            float k  = xS - xF;
            int  idx = (int)xF;                            // in [0,89] by clamp
            float yf = yk_s[idx * LDS_STRIDE + cA + j];
            float yc = yk_s[idx * LDS_STRIDE + LDS_STRIDE + cA + j];
            rA[j] = yf * (1.0f - k) + k * yc;
        }
#pragma unroll
        for (int j = 0; j < 4; ++j) {
            float xS = (xb[j] + 3.0f) * 15.0f;
            xS = fminf(fmaxf(xS, 1e-5f), upper);
            float xF = floorf(xS);
            float k  = xS - xF;
            int  idx = (int)xF;
            float yf = yk_s[idx * LDS_STRIDE + cB + j];
            float yc = yk_s[idx * LDS_STRIDE + LDS_STRIDE + cB + j];
            rB[j] = yf * (1.0f - k) + k * yc;
        }
        __builtin_nontemporal_store(rA, out4 + idx4);
        __builtin_nontemporal_store(rB, out4 + idxB);
    }
    // tail: remaining single float4s
    for (; idx4 < n4; idx4 += stride) {
        f32x4 xv = xv4[idx4];
        const int c0 = (idx4 * 4) % N_FLT;
        f32x4 r;
#pragma unroll
        for (int j = 0; j < 4; ++j) {
            float xS = (xv[j] + 3.0f) * 15.0f;
            xS = fminf(fmaxf(xS, 1e-5f), upper);
            float xF = floorf(xS);
            float k  = xS - xF;
            int  idx = (int)xF;
            float yf = yk_s[idx * LDS_STRIDE + c0 + j];
            float yc = yk_s[idx * LDS_STRIDE + LDS_STRIDE + c0 + j];
            r[j] = yf * (1.0f - k) + k * yc;
        }
        __builtin_nontemporal_store(r, out4 + idx4);
    }
}

extern "C" void kernel_launch(void* const* d_in, const int* in_sizes, int n_in,
                              void* d_out, int out_size, void* d_ws, size_t ws_size,
                              hipStream_t stream) {
    const float* x  = (const float*)d_in[0];
    const float* yk = (const float*)d_in[1];
    float* out = (float*)d_out;

    int n  = in_sizes[0];      // 16*256*256*48 = 50,331,648 (divisible by 4)
    int n4 = n / 4;

    const int block = 256;
    const int grid  = 2048;    // 256 CUs * 8 blocks; 24 float4/thread

    spline_interp_kernel<<<grid, block, 0, stream>>>(x, yk, out, n4);
}